// Round 3
// baseline (236.451 us; speedup 1.0000x reference)
//
#include <hip/hip_runtime.h>

// IDWT 2D (Haar 2x2 filter bank), R7.
//
// Evidence from R6 (first successful bench):
//   - dur_us 229.0 vs R4's 225.1: two very different fully-coalesced kernels
//     within 2% -> large fixed component in dur_us.
//   - rocprof top-5 = ALL __amd_rocclr_fillBufferAligned @ ~79.8 us,
//     WRITE_SIZE = 512 MiB @ 6.73 TB/s (84% peak). Our kernel absent from
//     top-5 => kernel dispatch < 79.5 us.
//   - Model: dur_us ~= 2 x 80 us poison-fills (harness, untouchable)
//     + ~69 us kernel. Kernel floor = 268 MB @ 6.3 TB/s ~= 43 us.
//
// R6 -> R7: attack the remaining kernel-side gap via VMEM width. Pixel
// ownership switches from (t*64 + L) to (4L + t):
//   - loads : 4x global_load_dwordx4 (one per subband), each instruction
//             1 KiB wave-contiguous (was 16x dword at 4 B/lane),
//   - stores: 4x global_store_dwordx4 at 64 B lane stride; each lane writes
//             exactly its own full 64 B line (offsets 64L + {0,16,32,48}),
//             so no partial-line write leakage.
// Output identity (unchanged): out float offset = 4*p + ab, p = flat input
// pixel index; i.e. out is exactly float4[p].
//
// Prediction: headroom-theory -> dur_us 205-215; floor-theory -> 229 +- 4,
// and next round concludes roofline-with-harness-floor.

typedef float floatx4 __attribute__((ext_vector_type(4)));

constexpr long SUB_STRIDE = 1L << 20;   // C*H*W floats = 4 MiB per subband
constexpr long P_TOTAL    = 8L << 20;   // B*C*H*W = 8,388,608 pixels

__global__ __launch_bounds__(256) void idwt2d_kernel(
    const float* __restrict__ x,
    const float* __restrict__ f,
    float* __restrict__ out)
{
    // Thread owns 4 CONSECUTIVE pixels q0 .. q0+3.
    const long tid = (long)blockIdx.x * blockDim.x + threadIdx.x;
    const long q0  = tid << 2;

    // Filters: wave-uniform (compiler emits scalar loads). f[k*4 + a*2 + b].
    floatx4 fv4[4];
#pragma unroll
    for (int k = 0; k < 4; ++k)
        fv4[k] = ((const floatx4*)f)[k];

    // All 4 pixels share one n: q0 is 4-aligned, 2^20 boundaries are too.
    const long n = q0 >> 20;

    // 4 loads: one dwordx4 per subband k at x[q0 + (3n+k)*2^20].
    // Each instruction: 64 lanes x 16 B contiguous = 1 KiB.
    floatx4 v[4];
#pragma unroll
    for (int k = 0; k < 4; ++k)
        v[k] = *(const floatx4*)(x + q0 + (3 * n + k) * SUB_STRIDE);

    // 4 stores: out = float4[pixel]; lane covers bytes [64L, 64L+64) of the
    // wave's 4 KiB output chunk -> full-line-per-lane.
    floatx4* o4 = (floatx4*)out + q0;
#pragma unroll
    for (int t = 0; t < 4; ++t) {
        floatx4 r;
#pragma unroll
        for (int ab = 0; ab < 4; ++ab)
            r[ab] = fv4[0][ab] * v[0][t] + fv4[1][ab] * v[1][t]
                  + fv4[2][ab] * v[2][t] + fv4[3][ab] * v[3][t];
        o4[t] = r;
    }
}

extern "C" void kernel_launch(void* const* d_in, const int* in_sizes, int n_in,
                              void* d_out, int out_size, void* d_ws, size_t ws_size,
                              hipStream_t stream)
{
    const float* x   = (const float*)d_in[0];
    const float* flt = (const float*)d_in[1];
    float* out       = (float*)d_out;

    const int block = 256;
    const int grid  = (int)(P_TOTAL / ((long)block * 4));  // 8192 blocks
    idwt2d_kernel<<<grid, block, 0, stream>>>(x, flt, out);
}

// Round 4
// 230.940 us; speedup vs baseline: 1.0239x; 1.0239x over previous
//
#include <hip/hip_runtime.h>

// IDWT 2D (Haar 2x2 filter bank), R8.
//
// Evidence through R7:
//   - Traffic is clean (WRITE exactly 128 MiB, FETCH 64 MiB w/ L3 hits), yet
//     effective rate 3.3 TB/s vs 6.3 copy ceiling; VALUBusy 3%. Latency-bound.
//   - VGPR_Count=20: too small to hold 4 in-flight dwordx4 loads + 16 filter
//     VGPRs -> compiler serialized the memory pipeline. MLP collapsed.
//   - R7's 64-partial-lines-per-instruction stores regressed vs R6's
//     contiguous stores (82 vs ~75 us).
//
// R8 changes:
//   1. Filters -> SGPR via readfirstlane (no per-pixel-group filter VMEM,
//      frees 16 VGPRs; FMAs read 1 SGPR + VGPRs, legal operand mix).
//   2. R6 ownership restored: wave handles 256-pixel chunks; lane L owns
//      pixels chunk+t*64+L. Loads: 16x dword, 256 B contiguous/instr.
//      Stores: 4x dwordx4, 1 KiB contiguous/instr (out is float4[pixel]).
//   3. Grid-stride steady state: 2048 blocks (8/CU, fully resident), each
//      block owns 4096 CONTIGUOUS pixels = 4 chunk-groups, software-pipelined
//      2 deep with named A/B buffers (static indices only -> stays in VGPRs).
//
// Prediction: VGPR 20->~56, kernel 82->55-65 us, dur_us 236->~210.

typedef float floatx4 __attribute__((ext_vector_type(4)));

constexpr long SUB_STRIDE = 1L << 20;   // C*H*W floats (4 MiB per subband)
constexpr long P_TOTAL    = 8L << 20;   // 8,388,608 pixels
constexpr int  BLOCKS     = 2048;       // 8 blocks/CU, all resident
constexpr int  PIX_PER_BLOCK = (int)(P_TOTAL / BLOCKS);  // 4096

#define LOAD_GROUP(dst, IT)                                            \
    _Pragma("unroll") for (int k = 0; k < 4; ++k)                      \
    _Pragma("unroll") for (int t = 0; t < 4; ++t)                      \
        dst[k][t] = xk[k][(IT) * 1024 + t * 64];

#define COMPUTE_STORE(src, IT)                                         \
    _Pragma("unroll") for (int t = 0; t < 4; ++t) {                    \
        floatx4 r;                                                     \
        _Pragma("unroll") for (int ab = 0; ab < 4; ++ab)               \
            r[ab] = fs[ab]      * src[0][t] + fs[4 + ab]  * src[1][t]  \
                  + fs[8 + ab]  * src[2][t] + fs[12 + ab] * src[3][t]; \
        o4[(IT) * 1024 + t * 64] = r;                                  \
    }

__global__ __launch_bounds__(256) void idwt2d_kernel(
    const float* __restrict__ x,
    const float* __restrict__ f,
    float* __restrict__ out)
{
    const int lane = threadIdx.x & 63;
    const int wv   = threadIdx.x >> 6;

    // Block owns pixels [PB, PB+4096). 4096 | 2^20, so n is block-uniform.
    const long PB = (long)blockIdx.x * PIX_PER_BLOCK;
    const long n  = PB >> 20;

    // Filters into SGPRs (wave-uniform by construction).
    float fs[16];
#pragma unroll
    for (int i = 0; i < 16; ++i)
        fs[i] = __uint_as_float(
            (unsigned)__builtin_amdgcn_readfirstlane((int)__float_as_uint(f[i])));

    // Per-thread stream bases. Thread offset within block chunk: wv*256+lane.
    const long toff = (long)wv * 256 + lane;
    const float* xk[4];
#pragma unroll
    for (int k = 0; k < 4; ++k)
        xk[k] = x + PB + (3 * n + k) * SUB_STRIDE + toff;
    floatx4* o4 = (floatx4*)out + PB + toff;   // out float offset = 4*pixel

    // Software pipeline, 2 deep, 4 groups of 1024 pixels. All indices static.
    float A[4][4], Bf[4][4];
    LOAD_GROUP(A, 0)
    LOAD_GROUP(Bf, 1)
    COMPUTE_STORE(A, 0)
    LOAD_GROUP(A, 2)
    COMPUTE_STORE(Bf, 1)
    LOAD_GROUP(Bf, 3)
    COMPUTE_STORE(A, 2)
    COMPUTE_STORE(Bf, 3)
}

extern "C" void kernel_launch(void* const* d_in, const int* in_sizes, int n_in,
                              void* d_out, int out_size, void* d_ws, size_t ws_size,
                              hipStream_t stream)
{
    const float* x   = (const float*)d_in[0];
    const float* flt = (const float*)d_in[1];
    float* out       = (float*)d_out;

    idwt2d_kernel<<<BLOCKS, 256, 0, stream>>>(x, flt, out);
}